// Round 1
// baseline (1198.298 us; speedup 1.0000x reference)
//
#include <hip/hip_runtime.h>
#include <cstddef>

#define B_  16
#define C_  512
#define N_  1024
#define NG  32
#define CPG 16
#define NH_ 8
#define DH  64

// ---------------- GroupNorm: one block per (batch, group) ----------------
__global__ __launch_bounds__(256) void gn_kernel(
    const float* __restrict__ x, const float* __restrict__ gamma,
    const float* __restrict__ beta, float* __restrict__ h) {
  int bg = blockIdx.x;
  int b = bg >> 5, g = bg & 31;
  size_t base = ((size_t)b * C_ + (size_t)g * CPG) * N_;
  const float4* x4 = (const float4*)(x + base);
  float4* h4 = (float4*)(h + base);
  int tid = threadIdx.x;

  float sum = 0.f, sq = 0.f;
  float4 vv[16];
#pragma unroll
  for (int i = 0; i < 16; i++) {
    float4 v = x4[tid + i * 256];
    vv[i] = v;
    sum += v.x + v.y + v.z + v.w;
    sq  += v.x * v.x + v.y * v.y + v.z * v.z + v.w * v.w;
  }
#pragma unroll
  for (int off = 32; off > 0; off >>= 1) {
    sum += __shfl_down(sum, off, 64);
    sq  += __shfl_down(sq, off, 64);
  }
  __shared__ float sm[4], sv[4];
  int lane = tid & 63, w = tid >> 6;
  if (lane == 0) { sm[w] = sum; sv[w] = sq; }
  __syncthreads();
  if (tid == 0) {
    float s = sm[0] + sm[1] + sm[2] + sm[3];
    float q = sv[0] + sv[1] + sv[2] + sv[3];
    float mean = s * (1.f / 16384.f);
    float var  = q * (1.f / 16384.f) - mean * mean;
    sm[0] = mean;
    sv[0] = rsqrtf(var + 1e-5f);
  }
  __syncthreads();
  float mean = sm[0], rstd = sv[0];
#pragma unroll
  for (int i = 0; i < 16; i++) {
    int c = g * CPG + i;
    float ga = gamma[c] * rstd;
    float be = beta[c] - mean * ga;
    float4 v = vv[i];
    float4 o;
    o.x = v.x * ga + be; o.y = v.y * ga + be;
    o.z = v.z * ga + be; o.w = v.w * ga + be;
    h4[tid + i * 256] = o;
  }
}

// ------- Batched GEMM: Out[b,m,n] = sum_k W[m,k]*In[b,k,n] + bias[m] (+resid) -------
// grid: (N/64, M/64, B), block 256. 64x64 tile, BK=16, 4x4 per thread.
__global__ __launch_bounds__(256) void gemm_kernel(
    const float* __restrict__ W, const float* __restrict__ bias,
    const float* __restrict__ In, const float* __restrict__ resid,
    float* __restrict__ Out, int M) {
  const int K = C_;
  int b  = blockIdx.z;
  int n0 = blockIdx.x * 64;
  int m0 = blockIdx.y * 64;
  const float* Ab = W + (size_t)m0 * K;
  const float* Bb = In + (size_t)b * K * N_ + n0;

  __shared__ float As[16][64];  // [k][m]
  __shared__ float Bs[16][64];  // [k][n]

  int tid = threadIdx.x;
  int tx = tid & 15, ty = tid >> 4;
  int arow = tid >> 2, acol = (tid & 3) << 2;   // A tile load: 64 rows x 16 k
  int brow = tid >> 4, bcol = (tid & 15) << 2;  // B tile load: 16 k x 64 n

  float acc[4][4] = {};

  for (int k0 = 0; k0 < K; k0 += 16) {
    float4 av = *(const float4*)(Ab + (size_t)arow * K + k0 + acol);
    float4 bv = *(const float4*)(Bb + (size_t)(k0 + brow) * N_ + bcol);
    __syncthreads();
    As[acol + 0][arow] = av.x;
    As[acol + 1][arow] = av.y;
    As[acol + 2][arow] = av.z;
    As[acol + 3][arow] = av.w;
    *(float4*)&Bs[brow][bcol] = bv;
    __syncthreads();
#pragma unroll
    for (int kk = 0; kk < 16; kk++) {
      float4 a  = *(const float4*)&As[kk][ty << 2];
      float4 bb = *(const float4*)&Bs[kk][tx << 2];
      acc[0][0] += a.x * bb.x; acc[0][1] += a.x * bb.y; acc[0][2] += a.x * bb.z; acc[0][3] += a.x * bb.w;
      acc[1][0] += a.y * bb.x; acc[1][1] += a.y * bb.y; acc[1][2] += a.y * bb.z; acc[1][3] += a.y * bb.w;
      acc[2][0] += a.z * bb.x; acc[2][1] += a.z * bb.y; acc[2][2] += a.z * bb.z; acc[2][3] += a.z * bb.w;
      acc[3][0] += a.w * bb.x; acc[3][1] += a.w * bb.y; acc[3][2] += a.w * bb.z; acc[3][3] += a.w * bb.w;
    }
  }

#pragma unroll
  for (int q = 0; q < 4; q++) {
    int m = m0 + (ty << 2) + q;
    float bi = bias[m];
    size_t off = ((size_t)b * M + m) * N_ + n0 + (tx << 2);
    float4 r;
    r.x = acc[q][0] + bi; r.y = acc[q][1] + bi;
    r.z = acc[q][2] + bi; r.w = acc[q][3] + bi;
    if (resid) {
      float4 rv = *(const float4*)(resid + off);
      r.x += rv.x; r.y += rv.y; r.z += rv.z; r.w += rv.w;
    }
    *(float4*)(Out + off) = r;
  }
}

// ------------- Flash attention: one block per (qtile, head, batch) -------------
// qkv layout: (B, 3*C, N) == (B,3,nh,d,N). ao layout: (B, C, N).
__global__ __launch_bounds__(256) void attn_kernel(
    const float* __restrict__ qkv, float* __restrict__ ao) {
  int qt = blockIdx.x, hh = blockIdx.y, b = blockIdx.z;
  const float* qp = qkv + ((size_t)b * 1536 + hh * DH) * N_ + qt * 64;
  const float* kp = qkv + ((size_t)b * 1536 + 512 + hh * DH) * N_;
  const float* vp = qkv + ((size_t)b * 1536 + 1024 + hh * DH) * N_;

  __shared__ float Qs[64][64];   // [d][qi]
  __shared__ float KPs[64][65];  // K phase: [d][kj]; P phase: [kj][qi]
  __shared__ float Vs[64][65];   // [kj][d]

  int tid = threadIdx.x;
  int tx = tid & 15, ty = tid >> 4;
  int lrow = tid >> 4, lcol = (tid & 15) << 2;

#pragma unroll
  for (int rr = lrow; rr < 64; rr += 16) {
    *(float4*)&Qs[rr][lcol] = *(const float4*)(qp + (size_t)rr * N_ + lcol);
  }

  float m_i[4], l_i[4], O[4][4];
#pragma unroll
  for (int q = 0; q < 4; q++) {
    m_i[q] = -1e30f; l_i[q] = 0.f;
#pragma unroll
    for (int r = 0; r < 4; r++) O[q][r] = 0.f;
  }

  for (int kt = 0; kt < 16; kt++) {
    __syncthreads();
#pragma unroll
    for (int rr = lrow; rr < 64; rr += 16) {
      float4 kv = *(const float4*)(kp + (size_t)rr * N_ + kt * 64 + lcol);
      KPs[rr][lcol + 0] = kv.x; KPs[rr][lcol + 1] = kv.y;
      KPs[rr][lcol + 2] = kv.z; KPs[rr][lcol + 3] = kv.w;
      float4 vv = *(const float4*)(vp + (size_t)rr * N_ + kt * 64 + lcol);
      Vs[lcol + 0][rr] = vv.x; Vs[lcol + 1][rr] = vv.y;
      Vs[lcol + 2][rr] = vv.z; Vs[lcol + 3][rr] = vv.w;
    }
    __syncthreads();

    float s[4][4] = {};
#pragma unroll 8
    for (int dd = 0; dd < 64; dd++) {
      float4 a = *(const float4*)&Qs[dd][ty << 2];
      float k0 = KPs[dd][(tx << 2) + 0];
      float k1 = KPs[dd][(tx << 2) + 1];
      float k2 = KPs[dd][(tx << 2) + 2];
      float k3 = KPs[dd][(tx << 2) + 3];
      s[0][0] += a.x * k0; s[0][1] += a.x * k1; s[0][2] += a.x * k2; s[0][3] += a.x * k3;
      s[1][0] += a.y * k0; s[1][1] += a.y * k1; s[1][2] += a.y * k2; s[1][3] += a.y * k3;
      s[2][0] += a.z * k0; s[2][1] += a.z * k1; s[2][2] += a.z * k2; s[2][3] += a.z * k3;
      s[3][0] += a.w * k0; s[3][1] += a.w * k1; s[3][2] += a.w * k2; s[3][3] += a.w * k3;
    }

    float mt[4], alpha[4], p[4][4], rs[4];
#pragma unroll
    for (int q = 0; q < 4; q++) {
#pragma unroll
      for (int r = 0; r < 4; r++) s[q][r] *= 0.125f;
      mt[q] = fmaxf(fmaxf(s[q][0], s[q][1]), fmaxf(s[q][2], s[q][3]));
    }
#pragma unroll
    for (int o = 1; o < 16; o <<= 1) {
#pragma unroll
      for (int q = 0; q < 4; q++) mt[q] = fmaxf(mt[q], __shfl_xor(mt[q], o, 64));
    }
#pragma unroll
    for (int q = 0; q < 4; q++) {
      float mn = fmaxf(m_i[q], mt[q]);
      alpha[q] = __expf(m_i[q] - mn);
      m_i[q] = mn;
      rs[q] = 0.f;
#pragma unroll
      for (int r = 0; r < 4; r++) { p[q][r] = __expf(s[q][r] - mn); rs[q] += p[q][r]; }
    }
#pragma unroll
    for (int o = 1; o < 16; o <<= 1) {
#pragma unroll
      for (int q = 0; q < 4; q++) rs[q] += __shfl_xor(rs[q], o, 64);
    }
#pragma unroll
    for (int q = 0; q < 4; q++) {
      l_i[q] = l_i[q] * alpha[q] + rs[q];
#pragma unroll
      for (int r = 0; r < 4; r++) O[q][r] *= alpha[q];
    }

    __syncthreads();  // all S reads of KPs done before P overwrite
#pragma unroll
    for (int q = 0; q < 4; q++)
#pragma unroll
      for (int r = 0; r < 4; r++) KPs[(tx << 2) + r][(ty << 2) + q] = p[q][r];
    __syncthreads();

#pragma unroll 8
    for (int j = 0; j < 64; j++) {
      float pr[4], vr[4];
#pragma unroll
      for (int q = 0; q < 4; q++) pr[q] = KPs[j][(ty << 2) + q];
#pragma unroll
      for (int r = 0; r < 4; r++) vr[r] = Vs[j][(tx << 2) + r];
#pragma unroll
      for (int q = 0; q < 4; q++)
#pragma unroll
        for (int r = 0; r < 4; r++) O[q][r] += pr[q] * vr[r];
    }
  }

#pragma unroll
  for (int q = 0; q < 4; q++) {
    float inv = 1.f / l_i[q];
#pragma unroll
    for (int r = 0; r < 4; r++) {
      size_t off = ((size_t)b * C_ + hh * DH + (tx << 2) + r) * N_ + qt * 64 + (ty << 2) + q;
      ao[off] = O[q][r] * inv;
    }
  }
}

extern "C" void kernel_launch(void* const* d_in, const int* in_sizes, int n_in,
                              void* d_out, int out_size, void* d_ws, size_t ws_size,
                              hipStream_t stream) {
  (void)in_sizes; (void)n_in; (void)out_size; (void)ws_size;
  const float* x      = (const float*)d_in[0];
  const float* gamma  = (const float*)d_in[1];
  const float* beta   = (const float*)d_in[2];
  const float* w_qkv  = (const float*)d_in[3];
  const float* b_qkv  = (const float*)d_in[4];
  const float* w_proj = (const float*)d_in[5];
  const float* b_proj = (const float*)d_in[6];
  float* out = (float*)d_out;

  float* h    = (float*)d_ws;                       // B*C*N fp32 = 33.5 MB
  float* qkvb = h + (size_t)B_ * C_ * N_;           // B*3C*N fp32 = 100.6 MB
  float* ao   = h;                                  // reuse h after QKV GEMM

  hipLaunchKernelGGL(gn_kernel, dim3(B_ * NG), dim3(256), 0, stream,
                     x, gamma, beta, h);
  hipLaunchKernelGGL(gemm_kernel, dim3(16, 24, 16), dim3(256), 0, stream,
                     w_qkv, b_qkv, h, (const float*)nullptr, qkvb, 3 * C_);
  hipLaunchKernelGGL(attn_kernel, dim3(16, 8, 16), dim3(256), 0, stream,
                     qkvb, ao);
  hipLaunchKernelGGL(gemm_kernel, dim3(16, 8, 16), dim3(256), 0, stream,
                     w_proj, b_proj, ao, x, out, C_);
}

// Round 2
// 655.688 us; speedup vs baseline: 1.8275x; 1.8275x over previous
//
#include <hip/hip_runtime.h>
#include <cstddef>

#define B_  16
#define C_  512
#define N_  1024
#define NG  32
#define CPG 16
#define NH_ 8
#define DH  64

typedef __attribute__((ext_vector_type(8))) __bf16 bf16x8;
typedef __attribute__((ext_vector_type(4))) float f32x4;

__device__ __forceinline__ unsigned short f2bf(float x) {
  unsigned u = __float_as_uint(x);
  return (unsigned short)((u + 0x7fffu + ((u >> 16) & 1u)) >> 16);
}
__device__ __forceinline__ float bf2f(unsigned short h) {
  return __uint_as_float(((unsigned)h) << 16);
}

// ---------------- GroupNorm: one block per (batch, group) ----------------
__global__ __launch_bounds__(256) void gn_kernel(
    const float* __restrict__ x, const float* __restrict__ gamma,
    const float* __restrict__ beta, float* __restrict__ h) {
  int bg = blockIdx.x;
  int b = bg >> 5, g = bg & 31;
  size_t base = ((size_t)b * C_ + (size_t)g * CPG) * N_;
  const float4* x4 = (const float4*)(x + base);
  float4* h4 = (float4*)(h + base);
  int tid = threadIdx.x;

  float sum = 0.f, sq = 0.f;
  float4 vv[16];
#pragma unroll
  for (int i = 0; i < 16; i++) {
    float4 v = x4[tid + i * 256];
    vv[i] = v;
    sum += v.x + v.y + v.z + v.w;
    sq  += v.x * v.x + v.y * v.y + v.z * v.z + v.w * v.w;
  }
#pragma unroll
  for (int off = 32; off > 0; off >>= 1) {
    sum += __shfl_down(sum, off, 64);
    sq  += __shfl_down(sq, off, 64);
  }
  __shared__ float sm[4], sv[4];
  int lane = tid & 63, w = tid >> 6;
  if (lane == 0) { sm[w] = sum; sv[w] = sq; }
  __syncthreads();
  if (tid == 0) {
    float s = sm[0] + sm[1] + sm[2] + sm[3];
    float q = sv[0] + sv[1] + sv[2] + sv[3];
    float mean = s * (1.f / 16384.f);
    float var  = q * (1.f / 16384.f) - mean * mean;
    sm[0] = mean;
    sv[0] = rsqrtf(var + 1e-5f);
  }
  __syncthreads();
  float mean = sm[0], rstd = sv[0];
#pragma unroll
  for (int i = 0; i < 16; i++) {
    int c = g * CPG + i;
    float ga = gamma[c] * rstd;
    float be = beta[c] - mean * ga;
    float4 v = vv[i];
    float4 o;
    o.x = v.x * ga + be; o.y = v.y * ga + be;
    o.z = v.z * ga + be; o.w = v.w * ga + be;
    h4[tid + i * 256] = o;
  }
}

// ------- Batched GEMM: Out[b,m,n] = sum_k W[m,k]*In[b,k,n] + bias[m] (+resid) -------
__global__ __launch_bounds__(256) void gemm_kernel(
    const float* __restrict__ W, const float* __restrict__ bias,
    const float* __restrict__ In, const float* __restrict__ resid,
    float* __restrict__ Out, int M) {
  const int K = C_;
  int b  = blockIdx.z;
  int n0 = blockIdx.x * 64;
  int m0 = blockIdx.y * 64;
  const float* Ab = W + (size_t)m0 * K;
  const float* Bb = In + (size_t)b * K * N_ + n0;

  __shared__ float As[16][64];
  __shared__ float Bs[16][64];

  int tid = threadIdx.x;
  int tx = tid & 15, ty = tid >> 4;
  int arow = tid >> 2, acol = (tid & 3) << 2;
  int brow = tid >> 4, bcol = (tid & 15) << 2;

  float acc[4][4] = {};

  for (int k0 = 0; k0 < K; k0 += 16) {
    float4 av = *(const float4*)(Ab + (size_t)arow * K + k0 + acol);
    float4 bv = *(const float4*)(Bb + (size_t)(k0 + brow) * N_ + bcol);
    __syncthreads();
    As[acol + 0][arow] = av.x;
    As[acol + 1][arow] = av.y;
    As[acol + 2][arow] = av.z;
    As[acol + 3][arow] = av.w;
    *(float4*)&Bs[brow][bcol] = bv;
    __syncthreads();
#pragma unroll
    for (int kk = 0; kk < 16; kk++) {
      float4 a  = *(const float4*)&As[kk][ty << 2];
      float4 bb = *(const float4*)&Bs[kk][tx << 2];
      acc[0][0] += a.x * bb.x; acc[0][1] += a.x * bb.y; acc[0][2] += a.x * bb.z; acc[0][3] += a.x * bb.w;
      acc[1][0] += a.y * bb.x; acc[1][1] += a.y * bb.y; acc[1][2] += a.y * bb.z; acc[1][3] += a.y * bb.w;
      acc[2][0] += a.z * bb.x; acc[2][1] += a.z * bb.y; acc[2][2] += a.z * bb.z; acc[2][3] += a.z * bb.w;
      acc[3][0] += a.w * bb.x; acc[3][1] += a.w * bb.y; acc[3][2] += a.w * bb.z; acc[3][3] += a.w * bb.w;
    }
  }

#pragma unroll
  for (int q = 0; q < 4; q++) {
    int m = m0 + (ty << 2) + q;
    float bi = bias[m];
    size_t off = ((size_t)b * M + m) * N_ + n0 + (tx << 2);
    float4 r;
    r.x = acc[q][0] + bi; r.y = acc[q][1] + bi;
    r.z = acc[q][2] + bi; r.w = acc[q][3] + bi;
    if (resid) {
      float4 rv = *(const float4*)(resid + off);
      r.x += rv.x; r.y += rv.y; r.z += rv.z; r.w += rv.w;
    }
    *(float4*)(Out + off) = r;
  }
}

// ------------- MFMA flash attention -------------
// Computes S^T (m=key, k=d, n=q) then O^T (m=d, k=key, n=q).
// Block: 256 threads = 4 waves; block owns 256 queries, wave owns 64 (4 n-tiles).
// LDS: Kt[key][d] (XOR-swizzled, bf16), Vs[d][key] (natural, bf16).
__global__ __launch_bounds__(256) void attn_mfma(
    const float* __restrict__ qkv, float* __restrict__ ao) {
  __shared__ __align__(16) unsigned short Kt[64 * 72];
  __shared__ __align__(16) unsigned short Vs[64 * 72];

  const int tid = threadIdx.x;
  const int wave = tid >> 6, lane = tid & 63;
  const int quad = lane >> 4, col = lane & 15;
  const int b = blockIdx.z, h = blockIdx.y;
  const int qblk = blockIdx.x * 256 + wave * 64;

  const float* qp = qkv + ((size_t)b * 1536 + h * DH) * N_;
  const float* kp = qp + (size_t)512 * N_;
  const float* vp = qp + (size_t)1024 * N_;

  // Q B-fragments: B[k=d][n=q], lane holds Q[32ks+8*quad+j][q], pre-scaled.
  bf16x8 qf[4][2];
#pragma unroll
  for (int nt = 0; nt < 4; nt++) {
    int qg = qblk + nt * 16 + col;
#pragma unroll
    for (int ks = 0; ks < 2; ks++) {
      union { unsigned short s[8]; bf16x8 v; } t;
#pragma unroll
      for (int j = 0; j < 8; j++) {
        int d = ks * 32 + quad * 8 + j;
        t.s[j] = f2bf(0.125f * qp[(size_t)d * N_ + qg]);
      }
      qf[nt][ks] = t.v;
    }
  }

  float m_i[4], l_i[4];
  f32x4 O[4][4];  // [mt over d][nt over q]
#pragma unroll
  for (int nt = 0; nt < 4; nt++) {
    m_i[nt] = -1e30f; l_i[nt] = 0.f;
#pragma unroll
    for (int mt = 0; mt < 4; mt++) O[mt][nt] = f32x4{0.f, 0.f, 0.f, 0.f};
  }

  const int sc = tid & 15, sd0 = tid >> 4;

  for (int kt = 0; kt < 16; kt++) {
    __syncthreads();
    // ---- stage K (transposed+swizzled) and V (natural) as bf16 ----
#pragma unroll
    for (int i = 0; i < 4; i++) {
      int d = sd0 + 16 * i;
      float4 kv = *(const float4*)(kp + (size_t)d * N_ + kt * 64 + sc * 4);
      float4 vv = *(const float4*)(vp + (size_t)d * N_ + kt * 64 + sc * 4);
      int sw = (sc >> 1) & 7;                       // == ((4*sc+j)>>3)&7 for j<4
      int dcol = (((d >> 3) ^ sw) << 3) | (d & 7);  // swizzled d position
      Kt[(4 * sc + 0) * 72 + dcol] = f2bf(kv.x);
      Kt[(4 * sc + 1) * 72 + dcol] = f2bf(kv.y);
      Kt[(4 * sc + 2) * 72 + dcol] = f2bf(kv.z);
      Kt[(4 * sc + 3) * 72 + dcol] = f2bf(kv.w);
      unsigned short* vrow = &Vs[d * 72 + 4 * sc];
      vrow[0] = f2bf(vv.x); vrow[1] = f2bf(vv.y);
      vrow[2] = f2bf(vv.z); vrow[3] = f2bf(vv.w);
    }
    __syncthreads();

    // ---- load K/V A-fragments (b128, conflict-even) ----
    bf16x8 kf[4][2], vf[4][2];
#pragma unroll
    for (int mt = 0; mt < 4; mt++) {
      int key = 16 * mt + col;
      int swr = (key >> 3) & 7;
#pragma unroll
      for (int ks = 0; ks < 2; ks++) {
        kf[mt][ks] = *(const bf16x8*)&Kt[key * 72 + (((ks * 4 + quad) ^ swr) << 3)];
        vf[mt][ks] = *(const bf16x8*)&Vs[key * 72 + ks * 32 + quad * 8];
      }
    }

#pragma unroll
    for (int nt = 0; nt < 4; nt++) {
      // S^T = Kt x Q : D[m=key][n=q]
      f32x4 sf[4];
#pragma unroll
      for (int mt = 0; mt < 4; mt++) sf[mt] = f32x4{0.f, 0.f, 0.f, 0.f};
#pragma unroll
      for (int ks = 0; ks < 2; ks++)
#pragma unroll
        for (int mt = 0; mt < 4; mt++)
          sf[mt] = __builtin_amdgcn_mfma_f32_16x16x32_bf16(kf[mt][ks], qf[nt][ks], sf[mt], 0, 0, 0);

      // online softmax over keys (lane holds 16 keys for its q; reduce quads)
      float mx = sf[0][0];
#pragma unroll
      for (int mt = 0; mt < 4; mt++)
#pragma unroll
        for (int r = 0; r < 4; r++) mx = fmaxf(mx, sf[mt][r]);
      mx = fmaxf(mx, __shfl_xor(mx, 16, 64));
      mx = fmaxf(mx, __shfl_xor(mx, 32, 64));
      float mn = fmaxf(m_i[nt], mx);
      float alpha = __expf(m_i[nt] - mn);
      m_i[nt] = mn;

      unsigned pAr[4], pBr[4];
      float lsum = 0.f;
#pragma unroll
      for (int mt = 0; mt < 4; mt++) {
        unsigned short h0 = f2bf(__expf(sf[mt][0] - mn));
        unsigned short h1 = f2bf(__expf(sf[mt][1] - mn));
        unsigned short h2 = f2bf(__expf(sf[mt][2] - mn));
        unsigned short h3 = f2bf(__expf(sf[mt][3] - mn));
        lsum += bf2f(h0) + bf2f(h1) + bf2f(h2) + bf2f(h3);
        pAr[mt] = (unsigned)h0 | ((unsigned)h1 << 16);
        pBr[mt] = (unsigned)h2 | ((unsigned)h3 << 16);
      }
      lsum += __shfl_xor(lsum, 16, 64);
      lsum += __shfl_xor(lsum, 32, 64);
      l_i[nt] = l_i[nt] * alpha + lsum;
#pragma unroll
      for (int mt = 0; mt < 4; mt++) {
        O[mt][nt][0] *= alpha; O[mt][nt][1] *= alpha;
        O[mt][nt][2] *= alpha; O[mt][nt][3] *= alpha;
      }

      // P^T redistribution C-layout -> B-layout via register shuffles
      int srcA = 32 * (quad & 1) + col;
      int srcB = srcA + 16;
      bool hiq = quad >= 2;
#pragma unroll
      for (int ks = 0; ks < 2; ks++) {
        unsigned d0a = (unsigned)__shfl((int)pAr[2 * ks], srcA, 64);
        unsigned d0b = (unsigned)__shfl((int)pAr[2 * ks + 1], srcA, 64);
        unsigned d1a = (unsigned)__shfl((int)pBr[2 * ks], srcA, 64);
        unsigned d1b = (unsigned)__shfl((int)pBr[2 * ks + 1], srcA, 64);
        unsigned d2a = (unsigned)__shfl((int)pAr[2 * ks], srcB, 64);
        unsigned d2b = (unsigned)__shfl((int)pAr[2 * ks + 1], srcB, 64);
        unsigned d3a = (unsigned)__shfl((int)pBr[2 * ks], srcB, 64);
        unsigned d3b = (unsigned)__shfl((int)pBr[2 * ks + 1], srcB, 64);
        union { unsigned u[4]; bf16x8 v; } pf;
        pf.u[0] = hiq ? d0b : d0a;
        pf.u[1] = hiq ? d1b : d1a;
        pf.u[2] = hiq ? d2b : d2a;
        pf.u[3] = hiq ? d3b : d3a;
#pragma unroll
        for (int mt = 0; mt < 4; mt++)
          O[mt][nt] = __builtin_amdgcn_mfma_f32_16x16x32_bf16(vf[mt][ks], pf.v, O[mt][nt], 0, 0, 0);
      }
    }
  }

  // epilogue: O^T[d][q] / l
#pragma unroll
  for (int nt = 0; nt < 4; nt++) {
    float inv = 1.f / l_i[nt];
    int qg = qblk + nt * 16 + col;
#pragma unroll
    for (int mt = 0; mt < 4; mt++) {
#pragma unroll
      for (int r = 0; r < 4; r++) {
        int d = 16 * mt + 4 * quad + r;
        ao[((size_t)(b * C_ + h * DH + d)) * N_ + qg] = O[mt][nt][r] * inv;
      }
    }
  }
}

extern "C" void kernel_launch(void* const* d_in, const int* in_sizes, int n_in,
                              void* d_out, int out_size, void* d_ws, size_t ws_size,
                              hipStream_t stream) {
  (void)in_sizes; (void)n_in; (void)out_size; (void)ws_size;
  const float* x      = (const float*)d_in[0];
  const float* gamma  = (const float*)d_in[1];
  const float* beta   = (const float*)d_in[2];
  const float* w_qkv  = (const float*)d_in[3];
  const float* b_qkv  = (const float*)d_in[4];
  const float* w_proj = (const float*)d_in[5];
  const float* b_proj = (const float*)d_in[6];
  float* out = (float*)d_out;

  float* h    = (float*)d_ws;
  float* qkvb = h + (size_t)B_ * C_ * N_;
  float* ao   = h;

  hipLaunchKernelGGL(gn_kernel, dim3(B_ * NG), dim3(256), 0, stream,
                     x, gamma, beta, h);
  hipLaunchKernelGGL(gemm_kernel, dim3(16, 24, 16), dim3(256), 0, stream,
                     w_qkv, b_qkv, h, (const float*)nullptr, qkvb, 3 * C_);
  hipLaunchKernelGGL(attn_mfma, dim3(4, 8, 16), dim3(256), 0, stream,
                     qkvb, ao);
  hipLaunchKernelGGL(gemm_kernel, dim3(16, 8, 16), dim3(256), 0, stream,
                     w_proj, b_proj, ao, x, out, C_);
}

// Round 3
// 271.887 us; speedup vs baseline: 4.4073x; 2.4116x over previous
//
#include <hip/hip_runtime.h>
#include <cstddef>

#define B_  16
#define C_  512
#define N_  1024

typedef __attribute__((ext_vector_type(8))) __bf16 bf16x8;
typedef __attribute__((ext_vector_type(4))) float f32x4;

__device__ __forceinline__ unsigned short f2bf(float x) {
  unsigned u = __float_as_uint(x);
  return (unsigned short)((u + 0x7fffu + ((u >> 16) & 1u)) >> 16);
}
__device__ __forceinline__ float bf2f(unsigned short h) {
  return __uint_as_float(((unsigned)h) << 16);
}

#define GLDS16(g, l)                                                            \
  __builtin_amdgcn_global_load_lds(                                             \
      (const __attribute__((address_space(1))) void*)(g),                       \
      (__attribute__((address_space(3))) void*)(l), 16, 0, 0)

// ---------- weight fp32 -> bf16 ----------
__global__ __launch_bounds__(256) void wconv_kernel(
    const float* __restrict__ wq, const float* __restrict__ wp,
    unsigned short* __restrict__ oq, unsigned short* __restrict__ op) {
  int i = blockIdx.x * 256 + threadIdx.x;  // float4 chunks
  const float4* src; unsigned short* dst; int off;
  if (i < 196608) { src = (const float4*)wq; dst = oq; off = i; }
  else            { src = (const float4*)wp; dst = op; off = i - 196608; }
  float4 v = src[off];
  union { unsigned short s[4]; ushort4 u; } o;
  o.s[0] = f2bf(v.x); o.s[1] = f2bf(v.y);
  o.s[2] = f2bf(v.z); o.s[3] = f2bf(v.w);
  *(ushort4*)(dst + (size_t)off * 4) = o.u;
}

// ---------- GroupNorm: writes hT[b][n][c] bf16 ----------
__global__ __launch_bounds__(256) void gn_kernel(
    const float* __restrict__ x, const float* __restrict__ gamma,
    const float* __restrict__ beta, unsigned short* __restrict__ hT) {
  int bg = blockIdx.x;
  int b = bg >> 5, g = bg & 31;
  size_t base = ((size_t)b * C_ + (size_t)g * 16) * N_;
  const float4* x4 = (const float4*)(x + base);
  int tid = threadIdx.x;

  float sum = 0.f, sq = 0.f;
  float4 vv[16];
#pragma unroll
  for (int i = 0; i < 16; i++) {
    float4 v = x4[tid + i * 256];
    vv[i] = v;
    sum += v.x + v.y + v.z + v.w;
    sq  += v.x * v.x + v.y * v.y + v.z * v.z + v.w * v.w;
  }
#pragma unroll
  for (int off = 32; off > 0; off >>= 1) {
    sum += __shfl_down(sum, off, 64);
    sq  += __shfl_down(sq, off, 64);
  }
  __shared__ float sm[4], sv[4];
  int lane = tid & 63, w = tid >> 6;
  if (lane == 0) { sm[w] = sum; sv[w] = sq; }
  __syncthreads();
  if (tid == 0) {
    float s = sm[0] + sm[1] + sm[2] + sm[3];
    float q = sv[0] + sv[1] + sv[2] + sv[3];
    float mean = s * (1.f / 16384.f);
    float var  = q * (1.f / 16384.f) - mean * mean;
    sm[0] = mean;
    sv[0] = rsqrtf(var + 1e-5f);
  }
  __syncthreads();
  float mean = sm[0], rstd = sv[0];

  union { unsigned short s[16]; uint4 u[2]; } row[4];
#pragma unroll
  for (int i = 0; i < 16; i++) {
    int c = g * 16 + i;
    float ga = gamma[c] * rstd;
    float be = beta[c] - mean * ga;
    float4 v = vv[i];
    row[0].s[i] = f2bf(v.x * ga + be);
    row[1].s[i] = f2bf(v.y * ga + be);
    row[2].s[i] = f2bf(v.z * ga + be);
    row[3].s[i] = f2bf(v.w * ga + be);
  }
#pragma unroll
  for (int j = 0; j < 4; j++) {
    uint4* dst = (uint4*)(hT + ((size_t)b * N_ + 4 * tid + j) * C_ + g * 16);
    dst[0] = row[j].u[0];
    dst[1] = row[j].u[1];
  }
}

// ---------- MFMA GEMM: Out[b,m,n] = sum_k W[m,k]*InT[b,n,k] + bias[m] (+resid) ----------
// m97 structure: 128x128 tile, BK=32, global_load_lds(16B), 4 waves of 64x64.
template <int OUT_BF16>
__global__ __launch_bounds__(256) void gemm_mfma(
    const unsigned short* __restrict__ Wb, const float* __restrict__ bias,
    const unsigned short* __restrict__ InT, const float* __restrict__ resid,
    void* __restrict__ Out, int M) {
  __shared__ __align__(16) unsigned short As[128 * 32];
  __shared__ __align__(16) unsigned short Bs[128 * 32];

  const int b = blockIdx.z;
  const int n0 = blockIdx.x * 128, m0 = blockIdx.y * 128;
  const int tid = threadIdx.x;
  const int lane = tid & 63, wave = tid >> 6;
  const int col = lane & 15, quad = lane >> 4;
  const int wm = (wave >> 1) << 6, wn = (wave & 1) << 6;

  const unsigned short* Ag = Wb + (size_t)m0 * C_;
  const unsigned short* Bg = InT + ((size_t)b * N_ + n0) * C_;

  const int r0 = tid >> 2, c0 = (tid & 3) << 3;  // 16B chunk: row, k-offset

  f32x4 acc[4][4];
#pragma unroll
  for (int i = 0; i < 4; i++)
#pragma unroll
    for (int j = 0; j < 4; j++) acc[i][j] = f32x4{0.f, 0.f, 0.f, 0.f};

  for (int k0 = 0; k0 < C_; k0 += 32) {
    __syncthreads();
    GLDS16(Ag + (size_t)r0 * C_ + k0 + c0,        &As[tid * 8]);
    GLDS16(Ag + (size_t)(r0 + 64) * C_ + k0 + c0, &As[(tid + 256) * 8]);
    GLDS16(Bg + (size_t)r0 * C_ + k0 + c0,        &Bs[tid * 8]);
    GLDS16(Bg + (size_t)(r0 + 64) * C_ + k0 + c0, &Bs[(tid + 256) * 8]);
    __syncthreads();

    bf16x8 af[4], bfr[4];
#pragma unroll
    for (int mt = 0; mt < 4; mt++)
      af[mt] = *(const bf16x8*)&As[(wm + mt * 16 + col) * 32 + quad * 8];
#pragma unroll
    for (int nt = 0; nt < 4; nt++)
      bfr[nt] = *(const bf16x8*)&Bs[(wn + nt * 16 + col) * 32 + quad * 8];
#pragma unroll
    for (int mt = 0; mt < 4; mt++)
#pragma unroll
      for (int nt = 0; nt < 4; nt++)
        acc[mt][nt] = __builtin_amdgcn_mfma_f32_16x16x32_bf16(
            af[mt], bfr[nt], acc[mt][nt], 0, 0, 0);
  }

#pragma unroll
  for (int mt = 0; mt < 4; mt++) {
    int mbase = m0 + wm + mt * 16 + quad * 4;
#pragma unroll
    for (int nt = 0; nt < 4; nt++) {
      int n = n0 + wn + nt * 16 + col;
#pragma unroll
      for (int r = 0; r < 4; r++) {
        int m = mbase + r;
        float v = acc[mt][nt][r] + bias[m];
        size_t off = ((size_t)b * M + m) * N_ + n;
        if constexpr (OUT_BF16) {
          ((unsigned short*)Out)[off] = f2bf(v);
        } else {
          ((float*)Out)[off] = v + resid[off];
        }
      }
    }
  }
}

// ---------- MFMA flash attention (bf16 qkv in, bf16 aoT out) ----------
__global__ __launch_bounds__(256) void attn_mfma(
    const unsigned short* __restrict__ qkv, unsigned short* __restrict__ aoT) {
  __shared__ __align__(16) unsigned short Kt[64 * 72];
  __shared__ __align__(16) unsigned short Vs[64 * 72];

  const int tid = threadIdx.x;
  const int wave = tid >> 6, lane = tid & 63;
  const int quad = lane >> 4, col = lane & 15;
  const int b = blockIdx.z, hh = blockIdx.y;
  const int qblk = blockIdx.x * 256 + wave * 64;

  const unsigned short* qp = qkv + ((size_t)b * 1536 + hh * 64) * N_;
  const unsigned short* kp = qp + (size_t)512 * N_;
  const unsigned short* vp = qp + (size_t)1024 * N_;

  bf16x8 qf[4][2];
#pragma unroll
  for (int nt = 0; nt < 4; nt++) {
    int qg = qblk + nt * 16 + col;
#pragma unroll
    for (int ks = 0; ks < 2; ks++) {
      union { unsigned short s[8]; bf16x8 v; } t;
#pragma unroll
      for (int j = 0; j < 8; j++) {
        int d = ks * 32 + quad * 8 + j;
        t.s[j] = qp[(size_t)d * N_ + qg];
      }
      qf[nt][ks] = t.v;
    }
  }

  float m_i[4], l_i[4];
  f32x4 O[4][4];
#pragma unroll
  for (int nt = 0; nt < 4; nt++) {
    m_i[nt] = -1e30f; l_i[nt] = 0.f;
#pragma unroll
    for (int mt = 0; mt < 4; mt++) O[mt][nt] = f32x4{0.f, 0.f, 0.f, 0.f};
  }

  const int sc = tid & 15, sd0 = tid >> 4;

  for (int kt = 0; kt < 16; kt++) {
    __syncthreads();
#pragma unroll
    for (int i = 0; i < 4; i++) {
      int d = sd0 + 16 * i;
      ushort4 kv = *(const ushort4*)(kp + (size_t)d * N_ + kt * 64 + sc * 4);
      ushort4 vv = *(const ushort4*)(vp + (size_t)d * N_ + kt * 64 + sc * 4);
      int sw = (sc >> 1) & 7;
      int dcol = (((d >> 3) ^ sw) << 3) | (d & 7);
      Kt[(4 * sc + 0) * 72 + dcol] = kv.x;
      Kt[(4 * sc + 1) * 72 + dcol] = kv.y;
      Kt[(4 * sc + 2) * 72 + dcol] = kv.z;
      Kt[(4 * sc + 3) * 72 + dcol] = kv.w;
      unsigned short* vrow = &Vs[d * 72 + 4 * sc];
      vrow[0] = kv.x * 0 + vv.x; vrow[1] = vv.y;
      vrow[2] = vv.z; vrow[3] = vv.w;
    }
    __syncthreads();

    bf16x8 kf[4][2], vf[4][2];
#pragma unroll
    for (int mt = 0; mt < 4; mt++) {
      int key = 16 * mt + col;
      int swr = (key >> 3) & 7;
#pragma unroll
      for (int ks = 0; ks < 2; ks++) {
        kf[mt][ks] = *(const bf16x8*)&Kt[key * 72 + (((ks * 4 + quad) ^ swr) << 3)];
        vf[mt][ks] = *(const bf16x8*)&Vs[key * 72 + ks * 32 + quad * 8];
      }
    }

#pragma unroll
    for (int nt = 0; nt < 4; nt++) {
      f32x4 sf[4];
#pragma unroll
      for (int mt = 0; mt < 4; mt++) sf[mt] = f32x4{0.f, 0.f, 0.f, 0.f};
#pragma unroll
      for (int ks = 0; ks < 2; ks++)
#pragma unroll
        for (int mt = 0; mt < 4; mt++)
          sf[mt] = __builtin_amdgcn_mfma_f32_16x16x32_bf16(kf[mt][ks], qf[nt][ks], sf[mt], 0, 0, 0);

#pragma unroll
      for (int mt = 0; mt < 4; mt++)
#pragma unroll
        for (int r = 0; r < 4; r++) sf[mt][r] *= 0.125f;

      float mx = sf[0][0];
#pragma unroll
      for (int mt = 0; mt < 4; mt++)
#pragma unroll
        for (int r = 0; r < 4; r++) mx = fmaxf(mx, sf[mt][r]);
      mx = fmaxf(mx, __shfl_xor(mx, 16, 64));
      mx = fmaxf(mx, __shfl_xor(mx, 32, 64));
      float mn = fmaxf(m_i[nt], mx);
      float alpha = __expf(m_i[nt] - mn);
      m_i[nt] = mn;

      unsigned pAr[4], pBr[4];
      float lsum = 0.f;
#pragma unroll
      for (int mt = 0; mt < 4; mt++) {
        unsigned short h0 = f2bf(__expf(sf[mt][0] - mn));
        unsigned short h1 = f2bf(__expf(sf[mt][1] - mn));
        unsigned short h2 = f2bf(__expf(sf[mt][2] - mn));
        unsigned short h3 = f2bf(__expf(sf[mt][3] - mn));
        lsum += bf2f(h0) + bf2f(h1) + bf2f(h2) + bf2f(h3);
        pAr[mt] = (unsigned)h0 | ((unsigned)h1 << 16);
        pBr[mt] = (unsigned)h2 | ((unsigned)h3 << 16);
      }
      lsum += __shfl_xor(lsum, 16, 64);
      lsum += __shfl_xor(lsum, 32, 64);
      l_i[nt] = l_i[nt] * alpha + lsum;
#pragma unroll
      for (int mt = 0; mt < 4; mt++) {
        O[mt][nt][0] *= alpha; O[mt][nt][1] *= alpha;
        O[mt][nt][2] *= alpha; O[mt][nt][3] *= alpha;
      }

      int srcA = 32 * (quad & 1) + col;
      int srcB = srcA + 16;
      bool hiq = quad >= 2;
#pragma unroll
      for (int ks = 0; ks < 2; ks++) {
        unsigned d0a = (unsigned)__shfl((int)pAr[2 * ks], srcA, 64);
        unsigned d0b = (unsigned)__shfl((int)pAr[2 * ks + 1], srcA, 64);
        unsigned d1a = (unsigned)__shfl((int)pBr[2 * ks], srcA, 64);
        unsigned d1b = (unsigned)__shfl((int)pBr[2 * ks + 1], srcA, 64);
        unsigned d2a = (unsigned)__shfl((int)pAr[2 * ks], srcB, 64);
        unsigned d2b = (unsigned)__shfl((int)pAr[2 * ks + 1], srcB, 64);
        unsigned d3a = (unsigned)__shfl((int)pBr[2 * ks], srcB, 64);
        unsigned d3b = (unsigned)__shfl((int)pBr[2 * ks + 1], srcB, 64);
        union { unsigned u[4]; bf16x8 v; } pf;
        pf.u[0] = hiq ? d0b : d0a;
        pf.u[1] = hiq ? d1b : d1a;
        pf.u[2] = hiq ? d2b : d2a;
        pf.u[3] = hiq ? d3b : d3a;
#pragma unroll
        for (int mt = 0; mt < 4; mt++)
          O[mt][nt] = __builtin_amdgcn_mfma_f32_16x16x32_bf16(vf[mt][ks], pf.v, O[mt][nt], 0, 0, 0);
      }
    }
  }

#pragma unroll
  for (int nt = 0; nt < 4; nt++) {
    float inv = 1.f / l_i[nt];
    int qg = qblk + nt * 16 + col;
    unsigned short* dst = aoT + ((size_t)b * N_ + qg) * C_ + hh * 64;
#pragma unroll
    for (int mt = 0; mt < 4; mt++) {
      union { unsigned short s[4]; ushort4 v; } o;
#pragma unroll
      for (int r = 0; r < 4; r++) o.s[r] = f2bf(O[mt][nt][r] * inv);
      *(ushort4*)(dst + mt * 16 + quad * 4) = o.v;
    }
  }
}

extern "C" void kernel_launch(void* const* d_in, const int* in_sizes, int n_in,
                              void* d_out, int out_size, void* d_ws, size_t ws_size,
                              hipStream_t stream) {
  (void)in_sizes; (void)n_in; (void)out_size; (void)ws_size;
  const float* x      = (const float*)d_in[0];
  const float* gamma  = (const float*)d_in[1];
  const float* beta   = (const float*)d_in[2];
  const float* w_qkv  = (const float*)d_in[3];
  const float* b_qkv  = (const float*)d_in[4];
  const float* w_proj = (const float*)d_in[5];
  const float* b_proj = (const float*)d_in[6];
  float* out = (float*)d_out;

  unsigned short* hT   = (unsigned short*)d_ws;                 // B*N*C bf16
  unsigned short* qkvb = hT + (size_t)B_ * N_ * C_;             // B*3C*N bf16
  unsigned short* aoT  = hT;                                    // reuse
  unsigned short* wqb  = qkvb + (size_t)B_ * 1536 * N_;         // 3C*C bf16
  unsigned short* wpb  = wqb + (size_t)1536 * 512;              // C*C bf16

  wconv_kernel<<<dim3(1024), dim3(256), 0, stream>>>(w_qkv, w_proj, wqb, wpb);
  gn_kernel<<<dim3(B_ * 32), dim3(256), 0, stream>>>(x, gamma, beta, hT);
  gemm_mfma<1><<<dim3(8, 12, 16), dim3(256), 0, stream>>>(
      wqb, b_qkv, hT, (const float*)nullptr, (void*)qkvb, 1536);
  attn_mfma<<<dim3(4, 8, 16), dim3(256), 0, stream>>>(qkvb, aoT);
  gemm_mfma<0><<<dim3(8, 4, 16), dim3(256), 0, stream>>>(
      wpb, b_proj, aoT, x, (void*)out, 512);
}

// Round 4
// 225.882 us; speedup vs baseline: 5.3050x; 1.2037x over previous
//
#include <hip/hip_runtime.h>
#include <cstddef>

#define B_  16
#define C_  512
#define N_  1024

typedef __attribute__((ext_vector_type(8))) __bf16 bf16x8;
typedef __attribute__((ext_vector_type(4))) float f32x4;
typedef __attribute__((ext_vector_type(4))) short s16x4;

__device__ __forceinline__ unsigned short f2bf(float x) {
  unsigned u = __float_as_uint(x);
  return (unsigned short)((u + 0x7fffu + ((u >> 16) & 1u)) >> 16);
}
__device__ __forceinline__ float bf2f(unsigned short h) {
  return __uint_as_float(((unsigned)h) << 16);
}

#define GLDS16(g, l)                                                            \
  __builtin_amdgcn_global_load_lds(                                             \
      (const __attribute__((address_space(1))) void*)(g),                       \
      (__attribute__((address_space(3))) void*)(l), 16, 0, 0)

// ---------- weight fp32 -> bf16 ----------
__global__ __launch_bounds__(256) void wconv_kernel(
    const float* __restrict__ wq, const float* __restrict__ wp,
    unsigned short* __restrict__ oq, unsigned short* __restrict__ op) {
  int i = blockIdx.x * 256 + threadIdx.x;  // float4 chunks
  const float4* src; unsigned short* dst; int off;
  if (i < 196608) { src = (const float4*)wq; dst = oq; off = i; }
  else            { src = (const float4*)wp; dst = op; off = i - 196608; }
  float4 v = src[off];
  union { unsigned short s[4]; ushort4 u; } o;
  o.s[0] = f2bf(v.x); o.s[1] = f2bf(v.y);
  o.s[2] = f2bf(v.z); o.s[3] = f2bf(v.w);
  *(ushort4*)(dst + (size_t)off * 4) = o.u;
}

// ---------- GroupNorm: writes hT[b][n][c] bf16 ----------
__global__ __launch_bounds__(256) void gn_kernel(
    const float* __restrict__ x, const float* __restrict__ gamma,
    const float* __restrict__ beta, unsigned short* __restrict__ hT) {
  int bg = blockIdx.x;
  int b = bg >> 5, g = bg & 31;
  size_t base = ((size_t)b * C_ + (size_t)g * 16) * N_;
  const float4* x4 = (const float4*)(x + base);
  int tid = threadIdx.x;

  float sum = 0.f, sq = 0.f;
  float4 vv[16];
#pragma unroll
  for (int i = 0; i < 16; i++) {
    float4 v = x4[tid + i * 256];
    vv[i] = v;
    sum += v.x + v.y + v.z + v.w;
    sq  += v.x * v.x + v.y * v.y + v.z * v.z + v.w * v.w;
  }
#pragma unroll
  for (int off = 32; off > 0; off >>= 1) {
    sum += __shfl_down(sum, off, 64);
    sq  += __shfl_down(sq, off, 64);
  }
  __shared__ float sm[4], sv[4];
  int lane = tid & 63, w = tid >> 6;
  if (lane == 0) { sm[w] = sum; sv[w] = sq; }
  __syncthreads();
  if (tid == 0) {
    float s = sm[0] + sm[1] + sm[2] + sm[3];
    float q = sv[0] + sv[1] + sv[2] + sv[3];
    float mean = s * (1.f / 16384.f);
    float var  = q * (1.f / 16384.f) - mean * mean;
    sm[0] = mean;
    sv[0] = rsqrtf(var + 1e-5f);
  }
  __syncthreads();
  float mean = sm[0], rstd = sv[0];

  union { unsigned short s[16]; uint4 u[2]; } row[4];
#pragma unroll
  for (int i = 0; i < 16; i++) {
    int c = g * 16 + i;
    float ga = gamma[c] * rstd;
    float be = beta[c] - mean * ga;
    float4 v = vv[i];
    row[0].s[i] = f2bf(v.x * ga + be);
    row[1].s[i] = f2bf(v.y * ga + be);
    row[2].s[i] = f2bf(v.z * ga + be);
    row[3].s[i] = f2bf(v.w * ga + be);
  }
#pragma unroll
  for (int j = 0; j < 4; j++) {
    uint4* dst = (uint4*)(hT + ((size_t)b * N_ + 4 * tid + j) * C_ + g * 16);
    dst[0] = row[j].u[0];
    dst[1] = row[j].u[1];
  }
}

// ---------- MFMA GEMM: Out[b,m,n] = sum_k W[m,k]*InT[b,n,k] + bias[m] (+resid) ----------
template <int OUT_BF16>
__global__ __launch_bounds__(256) void gemm_mfma(
    const unsigned short* __restrict__ Wb, const float* __restrict__ bias,
    const unsigned short* __restrict__ InT, const float* __restrict__ resid,
    void* __restrict__ Out, int M) {
  __shared__ __align__(16) unsigned short As[128 * 32];
  __shared__ __align__(16) unsigned short Bs[128 * 32];

  const int b = blockIdx.z;
  const int n0 = blockIdx.x * 128, m0 = blockIdx.y * 128;
  const int tid = threadIdx.x;
  const int lane = tid & 63, wave = tid >> 6;
  const int col = lane & 15, quad = lane >> 4;
  const int wm = (wave >> 1) << 6, wn = (wave & 1) << 6;

  const unsigned short* Ag = Wb + (size_t)m0 * C_;
  const unsigned short* Bg = InT + ((size_t)b * N_ + n0) * C_;

  const int r0 = tid >> 2, c0 = (tid & 3) << 3;

  f32x4 acc[4][4];
#pragma unroll
  for (int i = 0; i < 4; i++)
#pragma unroll
    for (int j = 0; j < 4; j++) acc[i][j] = f32x4{0.f, 0.f, 0.f, 0.f};

  for (int k0 = 0; k0 < C_; k0 += 32) {
    __syncthreads();
    GLDS16(Ag + (size_t)r0 * C_ + k0 + c0,        &As[tid * 8]);
    GLDS16(Ag + (size_t)(r0 + 64) * C_ + k0 + c0, &As[(tid + 256) * 8]);
    GLDS16(Bg + (size_t)r0 * C_ + k0 + c0,        &Bs[tid * 8]);
    GLDS16(Bg + (size_t)(r0 + 64) * C_ + k0 + c0, &Bs[(tid + 256) * 8]);
    __syncthreads();

    bf16x8 af[4], bfr[4];
#pragma unroll
    for (int mt = 0; mt < 4; mt++)
      af[mt] = *(const bf16x8*)&As[(wm + mt * 16 + col) * 32 + quad * 8];
#pragma unroll
    for (int nt = 0; nt < 4; nt++)
      bfr[nt] = *(const bf16x8*)&Bs[(wn + nt * 16 + col) * 32 + quad * 8];
#pragma unroll
    for (int mt = 0; mt < 4; mt++)
#pragma unroll
      for (int nt = 0; nt < 4; nt++)
        acc[mt][nt] = __builtin_amdgcn_mfma_f32_16x16x32_bf16(
            af[mt], bfr[nt], acc[mt][nt], 0, 0, 0);
  }

#pragma unroll
  for (int mt = 0; mt < 4; mt++) {
    int mbase = m0 + wm + mt * 16 + quad * 4;
#pragma unroll
    for (int nt = 0; nt < 4; nt++) {
      int n = n0 + wn + nt * 16 + col;
#pragma unroll
      for (int r = 0; r < 4; r++) {
        int m = mbase + r;
        float v = acc[mt][nt][r] + bias[m];
        size_t off = ((size_t)b * M + m) * N_ + n;
        if constexpr (OUT_BF16) {
          ((unsigned short*)Out)[off] = f2bf(v);
        } else {
          ((float*)Out)[off] = v + resid[off];
        }
      }
    }
  }
}

// ---------- MFMA flash attention, no-max softmax, 16x16x16 PV ----------
// S^T (m=key,k=d,n=q) via 16x16x32; P stays in C-layout which IS the B-layout
// of 16x16x16, so PV (O^T, m=d,k=key,n=q) needs zero cross-lane movement.
__global__ __launch_bounds__(256) void attn_mfma(
    const unsigned short* __restrict__ qkv, unsigned short* __restrict__ aoT) {
  __shared__ __align__(16) unsigned short Kt[64 * 72];
  __shared__ __align__(16) unsigned short Vs[64 * 72];

  const int tid = threadIdx.x;
  const int wave = tid >> 6, lane = tid & 63;
  const int quad = lane >> 4, col = lane & 15;
  const int b = blockIdx.z, hh = blockIdx.y;
  const int qblk = blockIdx.x * 256 + wave * 64;

  const unsigned short* qp = qkv + ((size_t)b * 1536 + hh * 64) * N_;
  const unsigned short* kp = qp + (size_t)512 * N_;
  const unsigned short* vp = qp + (size_t)1024 * N_;

  // Q B-fragments pre-scaled by 0.125 (exact: exponent shift under RNE).
  bf16x8 qf[4][2];
#pragma unroll
  for (int nt = 0; nt < 4; nt++) {
    int qg = qblk + nt * 16 + col;
#pragma unroll
    for (int ks = 0; ks < 2; ks++) {
      union { unsigned short s[8]; bf16x8 v; } t;
#pragma unroll
      for (int j = 0; j < 8; j++) {
        int d = ks * 32 + quad * 8 + j;
        t.s[j] = f2bf(0.125f * bf2f(qp[(size_t)d * N_ + qg]));
      }
      qf[nt][ks] = t.v;
    }
  }

  float l_i[4];
  f32x4 O[4][4];
#pragma unroll
  for (int nt = 0; nt < 4; nt++) {
    l_i[nt] = 0.f;
#pragma unroll
    for (int mt = 0; mt < 4; mt++) O[mt][nt] = f32x4{0.f, 0.f, 0.f, 0.f};
  }

  const int sc = tid & 15, sd0 = tid >> 4;

  for (int kt = 0; kt < 16; kt++) {
    __syncthreads();
#pragma unroll
    for (int i = 0; i < 4; i++) {
      int d = sd0 + 16 * i;
      ushort4 kv = *(const ushort4*)(kp + (size_t)d * N_ + kt * 64 + sc * 4);
      ushort4 vv = *(const ushort4*)(vp + (size_t)d * N_ + kt * 64 + sc * 4);
      int sw = (sc >> 1) & 7;
      int dcol = (((d >> 3) ^ sw) << 3) | (d & 7);
      Kt[(4 * sc + 0) * 72 + dcol] = kv.x;
      Kt[(4 * sc + 1) * 72 + dcol] = kv.y;
      Kt[(4 * sc + 2) * 72 + dcol] = kv.z;
      Kt[(4 * sc + 3) * 72 + dcol] = kv.w;
      unsigned short* vrow = &Vs[d * 72 + 4 * sc];
      vrow[0] = vv.x; vrow[1] = vv.y;
      vrow[2] = vv.z; vrow[3] = vv.w;
    }
    __syncthreads();

    // K A-fragments (16x16x32): b128, swizzled conflict-even
    bf16x8 kf[4][2];
#pragma unroll
    for (int mt = 0; mt < 4; mt++) {
      int key = 16 * mt + col;
      int swr = (key >> 3) & 7;
#pragma unroll
      for (int ks = 0; ks < 2; ks++)
        kf[mt][ks] = *(const bf16x8*)&Kt[key * 72 + (((ks * 4 + quad) ^ swr) << 3)];
    }
    // V A-fragments (16x16x16): lane holds V^T[d=16mt+col][key=16kc+quad*4+j]
    s16x4 vf[4][4];
#pragma unroll
    for (int mt = 0; mt < 4; mt++)
#pragma unroll
      for (int kc = 0; kc < 4; kc++)
        vf[mt][kc] = *(const s16x4*)&Vs[(16 * mt + col) * 72 + 16 * kc + quad * 4];

#pragma unroll
    for (int nt = 0; nt < 4; nt++) {
      f32x4 sf[4];
#pragma unroll
      for (int mt = 0; mt < 4; mt++) sf[mt] = f32x4{0.f, 0.f, 0.f, 0.f};
#pragma unroll
      for (int ks = 0; ks < 2; ks++)
#pragma unroll
        for (int mt = 0; mt < 4; mt++)
          sf[mt] = __builtin_amdgcn_mfma_f32_16x16x32_bf16(kf[mt][ks], qf[nt][ks], sf[mt], 0, 0, 0);

      // p = exp(s); pack to bf16 by truncation (1 v_perm per pair)
      s16x4 pb[4];
      float lsum = 0.f;
#pragma unroll
      for (int kc = 0; kc < 4; kc++) {
        float e0 = __expf(sf[kc][0]);
        float e1 = __expf(sf[kc][1]);
        float e2 = __expf(sf[kc][2]);
        float e3 = __expf(sf[kc][3]);
        lsum += (e0 + e1) + (e2 + e3);
        unsigned lo = __builtin_amdgcn_perm(__float_as_uint(e1), __float_as_uint(e0), 0x07060302u);
        unsigned hi = __builtin_amdgcn_perm(__float_as_uint(e3), __float_as_uint(e2), 0x07060302u);
        union { unsigned u[2]; s16x4 v; } t;
        t.u[0] = lo; t.u[1] = hi;
        pb[kc] = t.v;
      }
      l_i[nt] += lsum;

#pragma unroll
      for (int kc = 0; kc < 4; kc++)
#pragma unroll
        for (int mt = 0; mt < 4; mt++)
          O[mt][nt] = __builtin_amdgcn_mfma_f32_16x16x16bf16_1k(vf[mt][kc], pb[kc], O[mt][nt], 0, 0, 0);
    }
  }

#pragma unroll
  for (int nt = 0; nt < 4; nt++) {
    float ls = l_i[nt];
    ls += __shfl_xor(ls, 16, 64);
    ls += __shfl_xor(ls, 32, 64);
    float inv = 1.f / ls;
    int qg = qblk + nt * 16 + col;
    unsigned short* dst = aoT + ((size_t)b * N_ + qg) * C_ + hh * 64;
#pragma unroll
    for (int mt = 0; mt < 4; mt++) {
      union { unsigned short s[4]; ushort4 v; } o;
#pragma unroll
      for (int r = 0; r < 4; r++) o.s[r] = f2bf(O[mt][nt][r] * inv);
      *(ushort4*)(dst + mt * 16 + quad * 4) = o.v;
    }
  }
}

extern "C" void kernel_launch(void* const* d_in, const int* in_sizes, int n_in,
                              void* d_out, int out_size, void* d_ws, size_t ws_size,
                              hipStream_t stream) {
  (void)in_sizes; (void)n_in; (void)out_size; (void)ws_size;
  const float* x      = (const float*)d_in[0];
  const float* gamma  = (const float*)d_in[1];
  const float* beta   = (const float*)d_in[2];
  const float* w_qkv  = (const float*)d_in[3];
  const float* b_qkv  = (const float*)d_in[4];
  const float* w_proj = (const float*)d_in[5];
  const float* b_proj = (const float*)d_in[6];
  float* out = (float*)d_out;

  unsigned short* hT   = (unsigned short*)d_ws;                 // B*N*C bf16
  unsigned short* qkvb = hT + (size_t)B_ * N_ * C_;             // B*3C*N bf16
  unsigned short* aoT  = hT;                                    // reuse
  unsigned short* wqb  = qkvb + (size_t)B_ * 1536 * N_;         // 3C*C bf16
  unsigned short* wpb  = wqb + (size_t)1536 * 512;              // C*C bf16

  wconv_kernel<<<dim3(1024), dim3(256), 0, stream>>>(w_qkv, w_proj, wqb, wpb);
  gn_kernel<<<dim3(B_ * 32), dim3(256), 0, stream>>>(x, gamma, beta, hT);
  gemm_mfma<1><<<dim3(8, 12, 16), dim3(256), 0, stream>>>(
      wqb, b_qkv, hT, (const float*)nullptr, (void*)qkvb, 1536);
  attn_mfma<<<dim3(4, 8, 16), dim3(256), 0, stream>>>(qkvb, aoT);
  gemm_mfma<0><<<dim3(8, 4, 16), dim3(256), 0, stream>>>(
      wpb, b_proj, aoT, x, (void*)out, 512);
}